// Round 9
// baseline (132.819 us; speedup 1.0000x reference)
//
#include <hip/hip_runtime.h>
#include <stdint.h>

// DILATE loss, B=32, L=512, DIM=16, gamma=1e-3, alpha=0.5.
//
// Round-9 structure:
//   kA : D[b][j][i] column-major.
//   kFT: one wave per batch, SKEW-4 forward hard-min DP carrying R (DTW
//        value) and T (= sum (i-j)^2 along argmin path). Lane l owns rows
//        8l+1..8l+8; at macro-step T processes cols 4(T-l)..+3 (192 steps).
//        Boundary handoff lane l-1 -> l via DPP wave_shr:1 (VALU, ~4cyc)
//        instead of ds_bpermute (~100cyc). 2-slot register prefetch pinned
//        with sched_barrier(0) per step (R8's VGPR=60 proved the compiler
//        sank the staging loads -> exposed memory latency each step).
//        No validity masking: BIGF borders self-propagate (1e10 + D = 1e10),
//        invalid lanes' exports are consumed only by invalid lanes.
//   kC : combine -> scalar loss.
// Tie priority (unchanged): diag > up > left.

#define N 512
#define NB 32
#define BIGF 1e10f

typedef unsigned int u32;
typedef float f32x4 __attribute__((ext_vector_type(4)));

#if __has_builtin(__builtin_amdgcn_mov_dpp)
#define SHFL1(x) __int_as_float(__builtin_amdgcn_mov_dpp(__float_as_int(x), 0x138, 0xF, 0xF, true))
#else
#define SHFL1(x) __shfl_up((x), 1)
#endif

// ---------------- kA: pairwise squared distances, column-major -------------
__global__ __launch_bounds__(512) void kA(const float* __restrict__ inp,
                                          const float* __restrict__ tgt,
                                          float* __restrict__ Dg) {
    const int b = blockIdx.y;
    const int jc = blockIdx.x;         // group of 4 columns
    const int tid = (int)threadIdx.x;  // row index i0 in [0,512)
    __shared__ float xs[4][16];        // x[j] = inp[b,j]-inp[b,0]
    if (tid < 64) {
        int c = tid >> 4, d = tid & 15;
        int j = jc * 4 + c;
        xs[c][d] = inp[(((size_t)b * N + j) << 4) + d] -
                   inp[(((size_t)b * N) << 4) + d];
    }
    __syncthreads();
    const float4* t4 = (const float4*)(tgt + (((size_t)b * N + tid) << 4));
    float4 ta = t4[0], tb = t4[1], tc = t4[2], td = t4[3];
    float* out = Dg + ((size_t)b * N + (size_t)jc * 4) * N + tid;
#pragma unroll
    for (int c = 0; c < 4; ++c) {
        float s = 0.f, e;
        e = ta.x - xs[c][0];  s = fmaf(e, e, s);
        e = ta.y - xs[c][1];  s = fmaf(e, e, s);
        e = ta.z - xs[c][2];  s = fmaf(e, e, s);
        e = ta.w - xs[c][3];  s = fmaf(e, e, s);
        e = tb.x - xs[c][4];  s = fmaf(e, e, s);
        e = tb.y - xs[c][5];  s = fmaf(e, e, s);
        e = tb.z - xs[c][6];  s = fmaf(e, e, s);
        e = tb.w - xs[c][7];  s = fmaf(e, e, s);
        e = tc.x - xs[c][8];  s = fmaf(e, e, s);
        e = tc.y - xs[c][9];  s = fmaf(e, e, s);
        e = tc.z - xs[c][10]; s = fmaf(e, e, s);
        e = tc.w - xs[c][11]; s = fmaf(e, e, s);
        e = td.x - xs[c][12]; s = fmaf(e, e, s);
        e = td.y - xs[c][13]; s = fmaf(e, e, s);
        e = td.z - xs[c][14]; s = fmaf(e, e, s);
        e = td.w - xs[c][15]; s = fmaf(e, e, s);
        out[(size_t)c * N] = s;
    }
}

// ---------------- kFT: skew-4 forward DP with in-DP path sum ---------------
__global__ __launch_bounds__(64) void kFT(const float* __restrict__ Dg,
                                          float* __restrict__ acc) {
    const int b = blockIdx.x;
    const int l = (int)threadIdx.x;
    const float* Db = Dg + (size_t)b * N * N;

    f32x4 DA[2][4], DB[2][4];  // [slot][col q]: rows 0-3 / 4-7
    const float* pS[2];

#define LOADC(s_, Tt)                                                         \
    do {                                                                      \
        int c0_ = min(max(4 * ((Tt) - l), 0), 508);                           \
        const float* p_ = Db + ((size_t)c0_ << 9) + (l << 3);                 \
        DA[s_][0] = ((const f32x4*)p_)[0];        DB[s_][0] = ((const f32x4*)p_)[1]; \
        DA[s_][1] = ((const f32x4*)(p_ + 512))[0];  DB[s_][1] = ((const f32x4*)(p_ + 512))[1]; \
        DA[s_][2] = ((const f32x4*)(p_ + 1024))[0]; DB[s_][2] = ((const f32x4*)(p_ + 1024))[1]; \
        DA[s_][3] = ((const f32x4*)(p_ + 1536))[0]; DB[s_][3] = ((const f32x4*)(p_ + 1536))[1]; \
    } while (0)

#define LOADP(s_)                                                             \
    do {                                                                      \
        const float* p_ = pS[s_];                                             \
        DA[s_][0] = ((const f32x4*)p_)[0];        DB[s_][0] = ((const f32x4*)p_)[1]; \
        DA[s_][1] = ((const f32x4*)(p_ + 512))[0];  DB[s_][1] = ((const f32x4*)(p_ + 512))[1]; \
        DA[s_][2] = ((const f32x4*)(p_ + 1024))[0]; DB[s_][2] = ((const f32x4*)(p_ + 1024))[1]; \
        DA[s_][3] = ((const f32x4*)(p_ + 1536))[0]; DB[s_][3] = ((const f32x4*)(p_ + 1536))[1]; \
        pS[s_] += 4096; /* +8 cols */                                         \
    } while (0)

    float Rp_[8], Tp_[8];  // prev column (col 3 of previous step)
    float X[8], XT[8], Y[8], YT[8];
#pragma unroll
    for (int r = 0; r < 8; ++r) { Rp_[r] = BIGF; Tp_[r] = 0.f; }
    float sR0 = BIGF, sR1 = BIGF, sR2 = BIGF, sR3 = BIGF, sRold = BIGF;
    float tR0 = 0.f, tR1 = 0.f, tR2 = 0.f, tR3 = 0.f, tRold = 0.f;
    float db = (float)(12 * l);  // (i-j) base: db = 12l - 4T, -=4 per step
    float Rfin = 0.f, Tfin = 0.f;

    LOADC(0, 0); LOADC(1, 1);

    // one column of 8 rows: boundary scalars (upB,dgB / T: utB,dtB),
    // D halves DL/DH, prev col arrays pr/pt, out arrays cr/ct, d-base dbq
#define CELLS(upB, dgB, utB, dtB, DL, DH, pr, pt, cr, ct, dbq)                \
    _Pragma("unroll") for (int r = 0; r < 8; ++r) {                           \
        float up = (r == 0) ? (upB) : cr[r - 1];                              \
        float dg = (r == 0) ? (dgB) : pr[r - 1];                              \
        float lf = pr[r];                                                     \
        float ut = (r == 0) ? (utB) : ct[r - 1];                              \
        float dt = (r == 0) ? (dtB) : pt[r - 1];                              \
        float lt = pt[r];                                                     \
        float mn = fminf(up, fminf(dg, lf));                                  \
        float Ts = (mn == dg) ? dt : ((mn == up) ? ut : lt);                  \
        float dr = (dbq) + (float)r;                                          \
        ct[r] = fmaf(dr, dr, Ts);                                             \
        cr[r] = ((r < 4) ? (DL)[r & 3] : (DH)[r & 3]) + mn;                   \
    }

#define MSTEP(T_, s_, PH)                                                     \
    do {                                                                      \
        const int cg = (T_) - l;                                              \
        const bool z = (l == 0);                                              \
        float u0 = z ? BIGF : sR0, u1 = z ? BIGF : sR1;                       \
        float u2 = z ? BIGF : sR2, u3 = z ? BIGF : sR3;                       \
        float v0 = z ? 0.f : tR0, v1 = z ? 0.f : tR1;                         \
        float v2 = z ? 0.f : tR2, v3 = z ? 0.f : tR3;                         \
        float g0 = z ? (((PH) == 0 && (T_) == 0) ? 0.f : BIGF) : sRold;       \
        float h0 = z ? 0.f : tRold;                                           \
        CELLS(u0, g0, v0, h0, DA[s_][0], DB[s_][0], Rp_, Tp_, X, XT, db);     \
        float b0 = X[7], bt0 = XT[7];                                         \
        CELLS(u1, u0, v1, v0, DA[s_][1], DB[s_][1], X, XT, Y, YT, db - 1.f);  \
        float b1 = Y[7], bt1 = YT[7];                                         \
        CELLS(u2, u1, v2, v1, DA[s_][2], DB[s_][2], Y, YT, X, XT, db - 2.f);  \
        float b2 = X[7], bt2 = XT[7];                                         \
        CELLS(u3, u2, v3, v2, DA[s_][3], DB[s_][3], X, XT, Rp_, Tp_, db - 3.f); \
        float b3 = Rp_[7], bt3 = Tp_[7];                                      \
        if ((PH) == 2) {                                                      \
            Rfin = (cg == 127) ? Rp_[7] : Rfin;                               \
            Tfin = (cg == 127) ? Tp_[7] : Tfin;                               \
        }                                                                     \
        sRold = sR3; tRold = tR3;                                             \
        sR0 = SHFL1(b0); sR1 = SHFL1(b1); sR2 = SHFL1(b2); sR3 = SHFL1(b3);   \
        tR0 = SHFL1(bt0); tR1 = SHFL1(bt1); tR2 = SHFL1(bt2); tR3 = SHFL1(bt3); \
        db -= 4.0f;                                                           \
        if ((PH) == 1) { LOADP(s_); } else { LOADC(s_, (T_) + 2); }           \
        __builtin_amdgcn_sched_barrier(0); /* pin prefetch in this step */    \
    } while (0)

    // prologue T=0..63
    for (int T = 0; T < 64; T += 2) { MSTEP(T, 0, 0); MSTEP(T + 1, 1, 0); }
    // steady T=64..123 (all lanes valid; LOADP targets cols <= 500)
    pS[0] = Db + ((size_t)(4 * (66 - l)) << 9) + (l << 3);
    pS[1] = Db + ((size_t)(4 * (67 - l)) << 9) + (l << 3);
    for (int T = 64; T < 124; T += 2) { MSTEP(T, 0, 1); MSTEP(T + 1, 1, 1); }
    // epilogue T=124..191 (last real step T=190; clamped reloads)
    for (int T = 124; T < 192; T += 2) { MSTEP(T, 0, 2); MSTEP(T + 1, 1, 2); }
#undef MSTEP
#undef CELLS
#undef LOADC
#undef LOADP

    if (l == 63) {
        acc[b] = Rfin;       // Rp[N,N]: hard-DTW value
        acc[NB + b] = Tfin;  // sum (i-j)^2 along argmin path
    }
}

// ---------------- kC: combine over batches ---------------------------------
__global__ void kC(const float* __restrict__ acc, float* __restrict__ out) {
    const int l = (int)threadIdx.x;
    float vs = (l < NB) ? acc[l] : 0.f;
    float vt = (l < NB) ? acc[NB + l] : 0.f;
#pragma unroll
    for (int o = 32; o >= 1; o >>= 1) {
        vs += __shfl_down(vs, o);
        vt += __shfl_down(vt, o);
    }
    if (l == 0)
        out[0] = 0.5f * (vs / (float)NB) +
                 0.5f * (vt / ((float)NB * (float)(N * N)));
}

__global__ void kSentinel(float* out) { out[0] = -12345.0f; }

extern "C" void kernel_launch(void* const* d_in, const int* in_sizes, int n_in,
                              void* d_out, int out_size, void* d_ws, size_t ws_size,
                              hipStream_t stream) {
    const float* inp = (const float*)d_in[0];
    const float* tgt = (const float*)d_in[1];
    float* out = (float*)d_out;

    const size_t DSZ = (size_t)NB * N * N * sizeof(float);  // 32 MiB
    const size_t NEEDED = 256 + DSZ;
    if (ws_size < NEEDED) {
        kSentinel<<<1, 1, 0, stream>>>(out);
        return;
    }
    char* ws = (char*)d_ws;
    float* acc = (float*)ws;  // [0..31] shape, [32..63] temporal
    float* Dg = (float*)(ws + 256);

    kA<<<dim3(N / 4, NB), 512, 0, stream>>>(inp, tgt, Dg);
    kFT<<<NB, 64, 0, stream>>>(Dg, acc);
    kC<<<1, 64, 0, stream>>>(acc, out);
}